// Round 19
// baseline (367.448 us; speedup 1.0000x reference)
//
#include <hip/hip_runtime.h>
#include <hip/hip_fp16.h>

#define HIDDEN 768
#define HEADS 12
#define HDIM 64
#define SEQ 2048
#define BATCH 4
#define ORDER 5
#define LOG2E 1.44269504088896f

typedef _Float16 f16;
typedef _Float16 f16x8 __attribute__((ext_vector_type(8)));
typedef _Float16 f16x4 __attribute__((ext_vector_type(4)));
typedef __fp16 fp16x2 __attribute__((ext_vector_type(2)));   // cvt_pkrtz result type
typedef float f32x4 __attribute__((ext_vector_type(4)));

#define MFMA16x16x32(A, B, C) __builtin_amdgcn_mfma_f32_16x16x32_f16(A, B, C, 0, 0, 0)

#define GLD16(gptr, lptr)                                                     \
    __builtin_amdgcn_global_load_lds(                                         \
        (const __attribute__((address_space(1))) void*)(gptr),                \
        (__attribute__((address_space(3))) void*)(lptr), 16, 0, 0)

// ---------------------------------------------------------------------------
// Kernel 1: prep. (a) convert X -> Xh f16, Wq/Wk/Wv -> Wh[2304][768] f16;
// (b) Chebyshev bias table (x LOG2E).
// ---------------------------------------------------------------------------
#define NXG (8192 * 768 / 8)
#define NWG (768 * 768 / 8)
#define NCVT (NXG + 3 * NWG)
#define NBIAS (HEADS * (2 * SEQ - 1))

__global__ __launch_bounds__(256)
void prep_kernel(const float* __restrict__ X,
                 const float* __restrict__ Wq, const float* __restrict__ Wk,
                 const float* __restrict__ Wv, const float* __restrict__ alphas,
                 f16* __restrict__ Xh, f16* __restrict__ Wh,
                 float* __restrict__ biasTab)
{
    const int tid = blockIdx.x * 256 + threadIdx.x;
    if (tid < NCVT) {
        const float* src;
        f16* dst;
        size_t off;
        if (tid < NXG)               { src = X;  dst = Xh;              off = (size_t)tid * 8; }
        else if (tid < NXG + NWG)    { src = Wq; dst = Wh;              off = (size_t)(tid - NXG) * 8; }
        else if (tid < NXG + 2*NWG)  { src = Wk; dst = Wh + 768 * 768;  off = (size_t)(tid - NXG - NWG) * 8; }
        else                         { src = Wv; dst = Wh + 2*768*768;  off = (size_t)(tid - NXG - 2*NWG) * 8; }
        float4 a = *(const float4*)(src + off);
        float4 b = *(const float4*)(src + off + 4);
        f16x8 h;
        h[0] = (f16)a.x; h[1] = (f16)a.y; h[2] = (f16)a.z; h[3] = (f16)a.w;
        h[4] = (f16)b.x; h[5] = (f16)b.y; h[6] = (f16)b.z; h[7] = (f16)b.w;
        *(f16x8*)(dst + off) = h;
    } else {
        int idx = tid - NCVT;
        if (idx >= NBIAS) return;
        const int W = 2 * SEQ - 1;
        int h = idx / W;
        int t = idx - h * W;
        float x = (float)(t - (SEQ - 1)) / (float)(SEQ - 1);
        float tp = 1.0f;
        float tc = x;
        float acc = alphas[h * (ORDER + 1) + 0] * tp + alphas[h * (ORDER + 1) + 1] * tc;
#pragma unroll
        for (int k = 2; k <= ORDER; ++k) {
            float tn = 2.0f * x * tc - tp;
            acc += alphas[h * (ORDER + 1) + k] * tn;
            tp = tc; tc = tn;
        }
        biasTab[idx] = acc * LOG2E;
    }
}

// ---------------------------------------------------------------------------
// Kernel 2: fused QKV GEMM (m97 structure). V is written with keys PERMUTED
// within each 32-block: kpos = ((key>>2)&3)<<3 | ((key>>4)&1)<<2 | (key&3),
// so attention's PV B-operand is lane-local (no P LDS round-trip needed).
// ---------------------------------------------------------------------------
__global__ __launch_bounds__(256)
void qkv_kernel(const f16* __restrict__ Xh, const f16* __restrict__ Wh,
                const float* __restrict__ bq, const float* __restrict__ bk,
                const float* __restrict__ bv,
                f16* __restrict__ qf, f16* __restrict__ kf, f16* __restrict__ vtf)
{
    const int wgid = (blockIdx.x & 7) * 144 + (blockIdx.x >> 3);
    const int tileM = wgid / 18;
    const int tileN = wgid % 18;
    const int m0 = tileM * 128;
    const int n0g = tileN * 128;
    const int w = tileN / 6;
    const int nloc0 = n0g - w * 768;
    const float* __restrict__ bias = (w == 0) ? bq : (w == 1) ? bk : bv;

    __shared__ __align__(16) f16 sA[128][32];
    __shared__ __align__(16) f16 sB[128][32];

    const int t = threadIdx.x;
    const int lane = t & 63;
    const int wv = t >> 6;
    const int wm = wv >> 1, wn = wv & 1;
    const int fr = lane & 15;
    const int kg = lane >> 4;

    const int srow = lane >> 2;
    const int scol = (lane & 3) * 8;

    f32x4 acc[4][4];
#pragma unroll
    for (int i = 0; i < 4; ++i)
#pragma unroll
        for (int j = 0; j < 4; ++j) acc[i][j] = (f32x4)(0.0f);

    const f16* gA = Xh + (size_t)(m0 + wv * 32 + srow) * 768 + scol;
    const f16* gB = Wh + (size_t)(n0g + wv * 32 + srow) * 768 + scol;
    f16* lA0 = &sA[wv * 32][0];
    f16* lA1 = &sA[wv * 32 + 16][0];
    f16* lB0 = &sB[wv * 32][0];
    f16* lB1 = &sB[wv * 32 + 16][0];

    for (int kt = 0; kt < 768; kt += 32) {
        __syncthreads();
        GLD16(gA + kt, lA0);
        GLD16(gA + kt + 16 * 768, lA1);
        GLD16(gB + kt, lB0);
        GLD16(gB + kt + 16 * 768, lB1);
        __syncthreads();

        f16x8 af[4], bf[4];
#pragma unroll
        for (int i = 0; i < 4; ++i) {
            af[i] = *(const f16x8*)&sA[wm * 64 + i * 16 + fr][kg * 8];
            bf[i] = *(const f16x8*)&sB[wn * 64 + i * 16 + fr][kg * 8];
        }
#pragma unroll
        for (int mi = 0; mi < 4; ++mi)
#pragma unroll
            for (int ni = 0; ni < 4; ++ni)
                acc[mi][ni] = MFMA16x16x32(af[mi], bf[ni], acc[mi][ni]);
    }

    const int bb = m0 >> 11;
#pragma unroll
    for (int mi = 0; mi < 4; ++mi) {
        const int s0 = (m0 & 2047) + wm * 64 + mi * 16 + kg * 4;
        // V key-permutation (within 32-block; s0 % 4 == 0 so low bits are 0)
        const int u = s0 & 31;
        const int s0p = (s0 & ~31) | (((u >> 2) & 3) << 3) | (((u >> 4) & 1) << 2);
#pragma unroll
        for (int ni = 0; ni < 4; ++ni) {
            const int nloc = nloc0 + wn * 64 + ni * 16 + fr;
            const int hh = nloc >> 6, d = nloc & 63;
            const size_t bh = (size_t)bb * HEADS + hh;
            const float bc = bias[nloc];
            if (w == 2) {
                f16x4 pv;
#pragma unroll
                for (int r = 0; r < 4; ++r) pv[r] = (f16)(acc[mi][ni][r] + bc);
                *(f16x4*)&vtf[(bh * HDIM + d) * SEQ + s0p] = pv;
            } else if (w == 0) {
#pragma unroll
                for (int r = 0; r < 4; ++r)
                    qf[(bh * SEQ + s0 + r) * HDIM + d] =
                        (f16)((acc[mi][ni][r] + bc) * (0.125f * LOG2E));
            } else {
#pragma unroll
                for (int r = 0; r < 4; ++r)
                    kf[(bh * SEQ + s0 + r) * HDIM + d] = (f16)(acc[mi][ni][r] + bc);
            }
        }
    }
}

// ---------------------------------------------------------------------------
// Kernel 3: flash attention — R16 base with V read DIRECTLY from global/L2
// (XCD-resident; loads issued at tile start, consumed at PV) and K double-
// buffered in two named 8KB LDS arrays -> ONE barrier per 64-key tile.
// ---------------------------------------------------------------------------
struct __align__(16) SMem {
    union {
        struct {
            f16 KA[64][64];
            f16 KB[64][64];
        } k;                    // 16384 B
        float sO[4][16][72];    // 18432 B, epilogue transpose per-wave
    } u;
};

__global__ __launch_bounds__(256, 3)
void attn_kernel(const f16* __restrict__ qf, const f16* __restrict__ kf,
                 const f16* __restrict__ vtf, const float* __restrict__ biasTab,
                 float* __restrict__ out)
{
    // XCD-affine: all 16 q-tiles of one (b,h) land on one XCD.
    const int xcd = blockIdx.x & 7;
    const int ii = blockIdx.x >> 3;
    const int qt = ii & 15;
    const int bh = (ii >> 4) * 8 + xcd;     // bijective, 0..47
    const int h = bh % HEADS;
    const int b = bh / HEADS;
    const int q0 = qt * 128;

    __shared__ SMem sm;

    const int t = threadIdx.x;
    const int lane = t & 63;
    const int wv = t >> 6;
    const int fr = lane & 15;
    const int kg = lane >> 4;
    const int r7 = fr & 7;

    // Per-lane bias base (global, L1/L2-resident; VMEM pipe)
    const int ubl = kg * 4 - wv * 32 - fr + 127;
    const float* const gB = biasTab + (size_t)h * (2 * SEQ - 1) + 1920 - q0 + ubl;

    // Q fragments in registers (0.125*LOG2E folded in by qkv kernel)
    f16x8 aq[2][2];
#pragma unroll
    for (int s = 0; s < 2; ++s)
#pragma unroll
        for (int c = 0; c < 2; ++c)
            aq[s][c] = *(const f16x8*)(qf +
                ((size_t)bh * SEQ + q0 + wv * 32 + s * 16 + fr) * HDIM + c * 32 + kg * 8);

    f32x4 oacc[2][4];
    float lsum[2] = {0.0f, 0.0f};
#pragma unroll
    for (int s = 0; s < 2; ++s)
#pragma unroll
        for (int df = 0; df < 4; ++df) oacc[s][df] = (f32x4)(0.0f);

    // K staging: thread t covers row t>>2, chunks (t&3)*2 and +1 (XOR-swz)
    const int srow = t >> 2;
    const int scol = (t & 3) * 16;
    const int sw0 = 8 * (((t & 3) * 2) ^ (srow & 7));
    const int sw1 = 8 * (((t & 3) * 2 + 1) ^ (srow & 7));
    const f16* const gkb = kf + ((size_t)bh * SEQ + srow) * HDIM + scol;
    // V direct-read base: lane (fr,kg) reads rows df*16+fr, cols j0+kg*8 (+32)
    const f16* const gvb2 = vtf + ((size_t)bh * HDIM + fr) * SEQ + kg * 8;

    f16x8 rk0, rk1;
    auto stage_load = [&](int j0) {
        rk0 = *(const f16x8*)(gkb + (size_t)j0 * HDIM);
        rk1 = *(const f16x8*)(gkb + (size_t)j0 * HDIM + 8);
    };
    auto write_K = [&](f16 (&K)[64][64]) {
        *(f16x8*)&K[srow][sw0] = rk0;
        *(f16x8*)&K[srow][sw1] = rk1;
    };

    float rb[5][4];
    auto bias_load = [&](int j0, float (&dst)[5][4]) {
#pragma unroll
        for (int g = 0; g < 5; ++g)
#pragma unroll
            for (int r = 0; r < 4; ++r)
                dst[g][r] = gB[j0 + (g - 1) * 16 + r];
    };

    // One 64-key tile: V loads issue first (L2 latency hides under QK+softmax),
    // QK from K_lds, softmax/pack in-register, write next-K to other buffer,
    // PV from V regs.
    auto tile_compute = [&](const f16 (&K)[64][64], f16 (&Kn)[64][64],
                            int j0, bool wr) {
        // V direct loads (global/L2, consumed at PV)
        f16x8 vr[4][2];
#pragma unroll
        for (int df = 0; df < 4; ++df) {
            const f16* vb = gvb2 + (size_t)(df * 16) * SEQ + j0;
            vr[df][0] = *(const f16x8*)(vb);
            vr[df][1] = *(const f16x8*)(vb + 32);
        }

        // T[key][q] = K Q^T, accumulator initialized with the bias
        f32x4 tt[2][4];
#pragma unroll
        for (int s = 0; s < 2; ++s)
#pragma unroll
            for (int ni = 0; ni < 4; ++ni)
#pragma unroll
                for (int r = 0; r < 4; ++r) tt[s][ni][r] = rb[ni - s + 1][r];

        __builtin_amdgcn_s_setprio(1);
#pragma unroll
        for (int ni = 0; ni < 4; ++ni) {
            const f16* kb = &K[ni * 16 + fr][0];
            f16x8 bk0 = *(const f16x8*)(kb + 8 * (kg ^ r7));
            f16x8 bk1 = *(const f16x8*)(kb + 8 * ((kg + 4) ^ r7));
            tt[0][ni] = MFMA16x16x32(bk0, aq[0][0], tt[0][ni]);
            tt[0][ni] = MFMA16x16x32(bk1, aq[0][1], tt[0][ni]);
            tt[1][ni] = MFMA16x16x32(bk0, aq[1][0], tt[1][ni]);
            tt[1][ni] = MFMA16x16x32(bk1, aq[1][1], tt[1][ni]);
        }
        __builtin_amdgcn_s_setprio(0);

        // softmax (no max subtraction) + pack P into PV B-operands in-register
        union { fp16x2 h2[4]; f16x8 v8; } ap[2][2];   // [s][half]
#pragma unroll
        for (int s = 0; s < 2; ++s) {
            float ls = 0.0f;
            float pv[4][4];
#pragma unroll
            for (int ni = 0; ni < 4; ++ni)
#pragma unroll
                for (int r = 0; r < 4; ++r) {
                    float p = __builtin_amdgcn_exp2f(tt[s][ni][r]);
                    pv[ni][r] = p;
                    ls += p;
                }
#pragma unroll
            for (int m = 0; m < 2; ++m)
#pragma unroll
                for (int nr = 0; nr < 2; ++nr) {
                    const int ni = 2 * m + nr;
                    ap[s][m].h2[nr * 2 + 0] =
                        __builtin_amdgcn_cvt_pkrtz(pv[ni][0], pv[ni][1]);
                    ap[s][m].h2[nr * 2 + 1] =
                        __builtin_amdgcn_cvt_pkrtz(pv[ni][2], pv[ni][3]);
                }
            lsum[s] += ls;
        }

        // Next tile's K into the OTHER buffer (its readers all passed the
        // previous barrier; overlaps PV below).
        if (wr) write_K(Kn);

        // PV: O^T[d][q] += MFMA(V regs, P fragments)
        __builtin_amdgcn_s_setprio(1);
#pragma unroll
        for (int df = 0; df < 4; ++df) {
            oacc[0][df] = MFMA16x16x32(vr[df][0], ap[0][0].v8, oacc[0][df]);
            oacc[0][df] = MFMA16x16x32(vr[df][1], ap[0][1].v8, oacc[0][df]);
            oacc[1][df] = MFMA16x16x32(vr[df][0], ap[1][0].v8, oacc[1][df]);
            oacc[1][df] = MFMA16x16x32(vr[df][1], ap[1][1].v8, oacc[1][df]);
        }
        __builtin_amdgcn_s_setprio(0);
    };

    // prologue: K tile 0 -> KA
    stage_load(0);
    bias_load(0, rb);
    write_K(sm.u.k.KA);
    __syncthreads();

    float rbn[5][4];
    for (int jj = 0; jj < SEQ; jj += 128) {
        // tile jj (KA); prefetch K[jj+64] (always valid) -> KB
        stage_load(jj + 64);
        bias_load(jj + 64, rbn);
        tile_compute(sm.u.k.KA, sm.u.k.KB, jj, true);
#pragma unroll
        for (int g = 0; g < 5; ++g)
#pragma unroll
            for (int r = 0; r < 4; ++r) rb[g][r] = rbn[g][r];
        __syncthreads();     // KB visible; KA free for rewrite

        // tile jj+64 (KB); prefetch K[jj+128] -> KA
        const bool more = (jj + 128 < SEQ);
        if (more) {
            stage_load(jj + 128);
            bias_load(jj + 128, rbn);
        }
        tile_compute(sm.u.k.KB, sm.u.k.KA, jj + 64, more);
        if (more) {
#pragma unroll
            for (int g = 0; g < 5; ++g)
#pragma unroll
                for (int r = 0; r < 4; ++r) rb[g][r] = rbn[g][r];
        }
        __syncthreads();     // KA visible; KB free for rewrite
    }

    // Final l reduce across kg groups (keys partitioned by kg)
    float inv[2];
#pragma unroll
    for (int s = 0; s < 2; ++s) {
        float l = lsum[s];
        l += __shfl_xor(l, 16, 64);
        l += __shfl_xor(l, 32, 64);
        inv[s] = 1.0f / l;
    }

    // Epilogue transpose via per-wave sO regions (loop-end barrier separates
    // the last K reads from these writes).
#pragma unroll
    for (int s = 0; s < 2; ++s) {
#pragma unroll
        for (int df = 0; df < 4; ++df) {
            f32x4 v = oacc[s][df];
            v *= inv[s];
            *(f32x4*)&sm.u.sO[wv][fr][df * 16 + kg * 4] = v;
        }
        int row = lane >> 2;
        int cb = (lane & 3) * 16;
        float* dst = out + ((size_t)b * SEQ + q0 + wv * 32 + s * 16 + row) * HIDDEN
                         + h * HDIM + cb;
#pragma unroll
        for (int i = 0; i < 4; ++i) {
            f32x4 v = *(const f32x4*)&sm.u.sO[wv][row][cb + 4 * i];
            *(f32x4*)(dst + 4 * i) = v;
        }
    }
}

// ---------------------------------------------------------------------------
extern "C" void kernel_launch(void* const* d_in, const int* in_sizes, int n_in,
                              void* d_out, int out_size, void* d_ws, size_t ws_size,
                              hipStream_t stream) {
    const float* X      = (const float*)d_in[0];
    const float* Wq     = (const float*)d_in[1];
    const float* bq     = (const float*)d_in[2];
    const float* Wk     = (const float*)d_in[3];
    const float* bk     = (const float*)d_in[4];
    const float* Wv     = (const float*)d_in[5];
    const float* bv     = (const float*)d_in[6];
    const float* alphas = (const float*)d_in[7];
    float* out = (float*)d_out;

    const size_t nQ = (size_t)BATCH * HEADS * SEQ * HDIM;
    f16* qf  = (f16*)d_ws;
    f16* kf  = qf + nQ;
    f16* vtf = kf + nQ;
    float* biasTab = (float*)(vtf + nQ);
    f16* Xh = (f16*)(biasTab + 49152);
    f16* Wh = Xh + (size_t)8192 * 768;

    const int prep_threads = NCVT + NBIAS;
    hipLaunchKernelGGL(prep_kernel, dim3((prep_threads + 255) / 256), dim3(256), 0,
                       stream, X, Wq, Wk, Wv, alphas, Xh, Wh, biasTab);
    hipLaunchKernelGGL(qkv_kernel, dim3(1152), dim3(256), 0, stream,
                       Xh, Wh, bq, bk, bv, qf, kf, vtf);
    hipLaunchKernelGGL(attn_kernel, dim3(BATCH * HEADS * 16), dim3(256), 0, stream,
                       qf, kf, vtf, biasTab, out);
}

// Round 20
// 127.200 us; speedup vs baseline: 2.8887x; 2.8887x over previous
//
#include <hip/hip_runtime.h>
#include <hip/hip_fp16.h>

#define HIDDEN 768
#define HEADS 12
#define HDIM 64
#define SEQ 2048
#define BATCH 4
#define ORDER 5
#define LOG2E 1.44269504088896f

typedef _Float16 f16;
typedef _Float16 f16x8 __attribute__((ext_vector_type(8)));
typedef _Float16 f16x4 __attribute__((ext_vector_type(4)));
typedef __fp16 fp16x2 __attribute__((ext_vector_type(2)));   // cvt_pkrtz result type
typedef float f32x4 __attribute__((ext_vector_type(4)));

#define MFMA16x16x32(A, B, C) __builtin_amdgcn_mfma_f32_16x16x32_f16(A, B, C, 0, 0, 0)

#define GLD16(gptr, lptr)                                                     \
    __builtin_amdgcn_global_load_lds(                                         \
        (const __attribute__((address_space(1))) void*)(gptr),                \
        (__attribute__((address_space(3))) void*)(lptr), 16, 0, 0)

// ---------------------------------------------------------------------------
// Kernel 1: prep. (a) convert X -> Xh f16, Wq/Wk/Wv -> Wh[2304][768] f16;
// (b) Chebyshev bias table (x LOG2E).
// ---------------------------------------------------------------------------
#define NXG (8192 * 768 / 8)
#define NWG (768 * 768 / 8)
#define NCVT (NXG + 3 * NWG)
#define NBIAS (HEADS * (2 * SEQ - 1))

__global__ __launch_bounds__(256)
void prep_kernel(const float* __restrict__ X,
                 const float* __restrict__ Wq, const float* __restrict__ Wk,
                 const float* __restrict__ Wv, const float* __restrict__ alphas,
                 f16* __restrict__ Xh, f16* __restrict__ Wh,
                 float* __restrict__ biasTab)
{
    const int tid = blockIdx.x * 256 + threadIdx.x;
    if (tid < NCVT) {
        const float* src;
        f16* dst;
        size_t off;
        if (tid < NXG)               { src = X;  dst = Xh;              off = (size_t)tid * 8; }
        else if (tid < NXG + NWG)    { src = Wq; dst = Wh;              off = (size_t)(tid - NXG) * 8; }
        else if (tid < NXG + 2*NWG)  { src = Wk; dst = Wh + 768 * 768;  off = (size_t)(tid - NXG - NWG) * 8; }
        else                         { src = Wv; dst = Wh + 2*768*768;  off = (size_t)(tid - NXG - 2*NWG) * 8; }
        float4 a = *(const float4*)(src + off);
        float4 b = *(const float4*)(src + off + 4);
        f16x8 h;
        h[0] = (f16)a.x; h[1] = (f16)a.y; h[2] = (f16)a.z; h[3] = (f16)a.w;
        h[4] = (f16)b.x; h[5] = (f16)b.y; h[6] = (f16)b.z; h[7] = (f16)b.w;
        *(f16x8*)(dst + off) = h;
    } else {
        int idx = tid - NCVT;
        if (idx >= NBIAS) return;
        const int W = 2 * SEQ - 1;
        int h = idx / W;
        int t = idx - h * W;
        float x = (float)(t - (SEQ - 1)) / (float)(SEQ - 1);
        float tp = 1.0f;
        float tc = x;
        float acc = alphas[h * (ORDER + 1) + 0] * tp + alphas[h * (ORDER + 1) + 1] * tc;
#pragma unroll
        for (int k = 2; k <= ORDER; ++k) {
            float tn = 2.0f * x * tc - tp;
            acc += alphas[h * (ORDER + 1) + k] * tn;
            tp = tc; tc = tn;
        }
        biasTab[idx] = acc * LOG2E;
    }
}

// ---------------------------------------------------------------------------
// Kernel 2: fused QKV GEMM (m97 structure). V is written with keys PERMUTED
// within each 32-block: kpos = ((key>>2)&3)<<3 | ((key>>4)&1)<<2 | (key&3),
// so attention's PV B-operand is lane-local (no P LDS round-trip needed).
// ---------------------------------------------------------------------------
__global__ __launch_bounds__(256)
void qkv_kernel(const f16* __restrict__ Xh, const f16* __restrict__ Wh,
                const float* __restrict__ bq, const float* __restrict__ bk,
                const float* __restrict__ bv,
                f16* __restrict__ qf, f16* __restrict__ kf, f16* __restrict__ vtf)
{
    const int wgid = (blockIdx.x & 7) * 144 + (blockIdx.x >> 3);
    const int tileM = wgid / 18;
    const int tileN = wgid % 18;
    const int m0 = tileM * 128;
    const int n0g = tileN * 128;
    const int w = tileN / 6;
    const int nloc0 = n0g - w * 768;
    const float* __restrict__ bias = (w == 0) ? bq : (w == 1) ? bk : bv;

    __shared__ __align__(16) f16 sA[128][32];
    __shared__ __align__(16) f16 sB[128][32];

    const int t = threadIdx.x;
    const int lane = t & 63;
    const int wv = t >> 6;
    const int wm = wv >> 1, wn = wv & 1;
    const int fr = lane & 15;
    const int kg = lane >> 4;

    const int srow = lane >> 2;
    const int scol = (lane & 3) * 8;

    f32x4 acc[4][4];
#pragma unroll
    for (int i = 0; i < 4; ++i)
#pragma unroll
        for (int j = 0; j < 4; ++j) acc[i][j] = (f32x4)(0.0f);

    const f16* gA = Xh + (size_t)(m0 + wv * 32 + srow) * 768 + scol;
    const f16* gB = Wh + (size_t)(n0g + wv * 32 + srow) * 768 + scol;
    f16* lA0 = &sA[wv * 32][0];
    f16* lA1 = &sA[wv * 32 + 16][0];
    f16* lB0 = &sB[wv * 32][0];
    f16* lB1 = &sB[wv * 32 + 16][0];

    for (int kt = 0; kt < 768; kt += 32) {
        __syncthreads();
        GLD16(gA + kt, lA0);
        GLD16(gA + kt + 16 * 768, lA1);
        GLD16(gB + kt, lB0);
        GLD16(gB + kt + 16 * 768, lB1);
        __syncthreads();

        f16x8 af[4], bf[4];
#pragma unroll
        for (int i = 0; i < 4; ++i) {
            af[i] = *(const f16x8*)&sA[wm * 64 + i * 16 + fr][kg * 8];
            bf[i] = *(const f16x8*)&sB[wn * 64 + i * 16 + fr][kg * 8];
        }
#pragma unroll
        for (int mi = 0; mi < 4; ++mi)
#pragma unroll
            for (int ni = 0; ni < 4; ++ni)
                acc[mi][ni] = MFMA16x16x32(af[mi], bf[ni], acc[mi][ni]);
    }

    const int bb = m0 >> 11;
#pragma unroll
    for (int mi = 0; mi < 4; ++mi) {
        const int s0 = (m0 & 2047) + wm * 64 + mi * 16 + kg * 4;
        // V key-permutation (within 32-block; s0 % 4 == 0 so low bits are 0)
        const int u = s0 & 31;
        const int s0p = (s0 & ~31) | (((u >> 2) & 3) << 3) | (((u >> 4) & 1) << 2);
#pragma unroll
        for (int ni = 0; ni < 4; ++ni) {
            const int nloc = nloc0 + wn * 64 + ni * 16 + fr;
            const int hh = nloc >> 6, d = nloc & 63;
            const size_t bh = (size_t)bb * HEADS + hh;
            const float bc = bias[nloc];
            if (w == 2) {
                f16x4 pv;
#pragma unroll
                for (int r = 0; r < 4; ++r) pv[r] = (f16)(acc[mi][ni][r] + bc);
                *(f16x4*)&vtf[(bh * HDIM + d) * SEQ + s0p] = pv;
            } else if (w == 0) {
#pragma unroll
                for (int r = 0; r < 4; ++r)
                    qf[(bh * SEQ + s0 + r) * HDIM + d] =
                        (f16)((acc[mi][ni][r] + bc) * (0.125f * LOG2E));
            } else {
#pragma unroll
                for (int r = 0; r < 4; ++r)
                    kf[(bh * SEQ + s0 + r) * HDIM + d] = (f16)(acc[mi][ni][r] + bc);
            }
        }
    }
}

// ---------------------------------------------------------------------------
// Kernel 3: flash attention — R16 champion: key-permuted V + in-register P
// (no sP LDS round-trip), single KV buffer, reg-staged load-early/write-late,
// XCD-affine grid, bias from global as MFMA C-init, XOR-swizzled K/VT.
// ---------------------------------------------------------------------------
struct __align__(16) SMem {
    union {
        struct {
            f16 sK[64][64];
            f16 sVT[64][64];
        } kv;                   // 16384 B
        float sO[4][16][72];    // 18432 B, epilogue transpose per-wave
    } u;
};

__global__ __launch_bounds__(256, 3)
void attn_kernel(const f16* __restrict__ qf, const f16* __restrict__ kf,
                 const f16* __restrict__ vtf, const float* __restrict__ biasTab,
                 float* __restrict__ out)
{
    // XCD-affine: all 16 q-tiles of one (b,h) land on one XCD.
    const int xcd = blockIdx.x & 7;
    const int ii = blockIdx.x >> 3;
    const int qt = ii & 15;
    const int bh = (ii >> 4) * 8 + xcd;     // bijective, 0..47
    const int h = bh % HEADS;
    const int b = bh / HEADS;
    const int q0 = qt * 128;

    __shared__ SMem sm;

    const int t = threadIdx.x;
    const int lane = t & 63;
    const int wv = t >> 6;
    const int fr = lane & 15;
    const int kg = lane >> 4;
    const int r7 = fr & 7;

    // Per-lane bias base (global, L1/L2-resident; VMEM pipe)
    const int ubl = kg * 4 - wv * 32 - fr + 127;
    const float* const gB = biasTab + (size_t)h * (2 * SEQ - 1) + 1920 - q0 + ubl;

    // Q fragments in registers (0.125*LOG2E folded in by qkv kernel)
    f16x8 aq[2][2];
#pragma unroll
    for (int s = 0; s < 2; ++s)
#pragma unroll
        for (int c = 0; c < 2; ++c)
            aq[s][c] = *(const f16x8*)(qf +
                ((size_t)bh * SEQ + q0 + wv * 32 + s * 16 + fr) * HDIM + c * 32 + kg * 8);

    f32x4 oacc[2][4];
    float lsum[2] = {0.0f, 0.0f};
#pragma unroll
    for (int s = 0; s < 2; ++s)
#pragma unroll
        for (int df = 0; df < 4; ++df) oacc[s][df] = (f32x4)(0.0f);

    // staging geometry: thread t covers row t>>2, chunks (t&3)*2 and +1
    const int srow = t >> 2;
    const int scol = (t & 3) * 16;
    const int sw0 = 8 * (((t & 3) * 2) ^ (srow & 7));
    const int sw1 = 8 * (((t & 3) * 2 + 1) ^ (srow & 7));
    const f16* const gkb = kf + ((size_t)bh * SEQ + srow) * HDIM + scol;
    const f16* const gvb = vtf + ((size_t)bh * HDIM + srow) * SEQ + scol;

    f16x8 rk0, rk1, rv0, rv1;
    auto stage_load = [&](int j0) {
        rk0 = *(const f16x8*)(gkb + (size_t)j0 * HDIM);
        rk1 = *(const f16x8*)(gkb + (size_t)j0 * HDIM + 8);
        rv0 = *(const f16x8*)(gvb + j0);
        rv1 = *(const f16x8*)(gvb + j0 + 8);
    };
    auto stage_write = [&]() {
        *(f16x8*)&sm.u.kv.sK[srow][sw0]  = rk0;
        *(f16x8*)&sm.u.kv.sK[srow][sw1]  = rk1;
        *(f16x8*)&sm.u.kv.sVT[srow][sw0] = rv0;
        *(f16x8*)&sm.u.kv.sVT[srow][sw1] = rv1;
    };

    float rb[5][4];
    auto bias_load = [&](int j0, float (&dst)[5][4]) {
#pragma unroll
        for (int g = 0; g < 5; ++g)
#pragma unroll
            for (int r = 0; r < 4; ++r)
                dst[g][r] = gB[j0 + (g - 1) * 16 + r];
    };

    // prologue: tile 0 + its bias
    stage_load(0);
    bias_load(0, rb);
    stage_write();
    __syncthreads();

    for (int j0 = 0; j0 < SEQ; j0 += 64) {
        const bool more = (j0 + 64 < SEQ);
        float rbn[5][4];
        if (more) {
            stage_load(j0 + 64);
            bias_load(j0 + 64, rbn);
        }

        // T[key][q] = K Q^T, accumulator initialized with the bias
        f32x4 tt[2][4];
#pragma unroll
        for (int s = 0; s < 2; ++s)
#pragma unroll
            for (int ni = 0; ni < 4; ++ni)
#pragma unroll
                for (int r = 0; r < 4; ++r) tt[s][ni][r] = rb[ni - s + 1][r];

        __builtin_amdgcn_s_setprio(1);
#pragma unroll
        for (int ni = 0; ni < 4; ++ni) {
            const f16* kb = &sm.u.kv.sK[ni * 16 + fr][0];
            f16x8 bk0 = *(const f16x8*)(kb + 8 * (kg ^ r7));
            f16x8 bk1 = *(const f16x8*)(kb + 8 * ((kg + 4) ^ r7));
            tt[0][ni] = MFMA16x16x32(bk0, aq[0][0], tt[0][ni]);
            tt[0][ni] = MFMA16x16x32(bk1, aq[0][1], tt[0][ni]);
            tt[1][ni] = MFMA16x16x32(bk0, aq[1][0], tt[1][ni]);
            tt[1][ni] = MFMA16x16x32(bk1, aq[1][1], tt[1][ni]);
        }
        __builtin_amdgcn_s_setprio(0);

        // softmax (no max subtraction) + pack P directly into PV B-operands.
        // Lane (fr,kg) holds P[key=ni*16+kg*4+r][q=s*16+fr]; vtf's key
        // permutation (kpos = kg*8 + (ni&1)*4 + r, half = ni>>1) makes these
        // exactly the B-fragment elements k = kg*8+j. No LDS round-trip.
        union { fp16x2 h2[4]; f16x8 v8; } ap[2][2];   // [s][half]
#pragma unroll
        for (int s = 0; s < 2; ++s) {
            float ls = 0.0f;
            float pv[4][4];
#pragma unroll
            for (int ni = 0; ni < 4; ++ni)
#pragma unroll
                for (int r = 0; r < 4; ++r) {
                    float p = __builtin_amdgcn_exp2f(tt[s][ni][r]);
                    pv[ni][r] = p;
                    ls += p;
                }
#pragma unroll
            for (int m = 0; m < 2; ++m)
#pragma unroll
                for (int nr = 0; nr < 2; ++nr) {
                    const int ni = 2 * m + nr;
                    ap[s][m].h2[nr * 2 + 0] =
                        __builtin_amdgcn_cvt_pkrtz(pv[ni][0], pv[ni][1]);
                    ap[s][m].h2[nr * 2 + 1] =
                        __builtin_amdgcn_cvt_pkrtz(pv[ni][2], pv[ni][3]);
                }
            lsum[s] += ls;
        }

        // PV: O^T[d][q] += MFMA(VT rows, P fragments)
        __builtin_amdgcn_s_setprio(1);
#pragma unroll
        for (int df = 0; df < 4; ++df) {
            const f16* vb = &sm.u.kv.sVT[df * 16 + fr][0];
            f16x8 bv0 = *(const f16x8*)(vb + 8 * (kg ^ r7));
            f16x8 bv1 = *(const f16x8*)(vb + 8 * ((kg + 4) ^ r7));
            oacc[0][df] = MFMA16x16x32(bv0, ap[0][0].v8, oacc[0][df]);
            oacc[0][df] = MFMA16x16x32(bv1, ap[0][1].v8, oacc[0][df]);
            oacc[1][df] = MFMA16x16x32(bv0, ap[1][0].v8, oacc[1][df]);
            oacc[1][df] = MFMA16x16x32(bv1, ap[1][1].v8, oacc[1][df]);
        }
        __builtin_amdgcn_s_setprio(0);

        __syncthreads();               // all waves done reading sK/sVT
        if (more) {
            stage_write();             // regs landed during compute
#pragma unroll
            for (int g = 0; g < 5; ++g)
#pragma unroll
                for (int r = 0; r < 4; ++r) rb[g][r] = rbn[g][r];
            __syncthreads();           // next tile visible
        }
    }

    // Final l reduce across kg groups (keys partitioned by kg)
    float inv[2];
#pragma unroll
    for (int s = 0; s < 2; ++s) {
        float l = lsum[s];
        l += __shfl_xor(l, 16, 64);
        l += __shfl_xor(l, 32, 64);
        inv[s] = 1.0f / l;
    }

    __syncthreads();   // safe to reuse kv region as sO
#pragma unroll
    for (int s = 0; s < 2; ++s) {
#pragma unroll
        for (int df = 0; df < 4; ++df) {
            f32x4 v = oacc[s][df];
            v *= inv[s];
            *(f32x4*)&sm.u.sO[wv][fr][df * 16 + kg * 4] = v;
        }
        int row = lane >> 2;
        int cb = (lane & 3) * 16;
        float* dst = out + ((size_t)b * SEQ + q0 + wv * 32 + s * 16 + row) * HIDDEN
                         + h * HDIM + cb;
#pragma unroll
        for (int i = 0; i < 4; ++i) {
            f32x4 v = *(const f32x4*)&sm.u.sO[wv][row][cb + 4 * i];
            *(f32x4*)(dst + 4 * i) = v;
        }
    }
}

// ---------------------------------------------------------------------------
extern "C" void kernel_launch(void* const* d_in, const int* in_sizes, int n_in,
                              void* d_out, int out_size, void* d_ws, size_t ws_size,
                              hipStream_t stream) {
    const float* X      = (const float*)d_in[0];
    const float* Wq     = (const float*)d_in[1];
    const float* bq     = (const float*)d_in[2];
    const float* Wk     = (const float*)d_in[3];
    const float* bk     = (const float*)d_in[4];
    const float* Wv     = (const float*)d_in[5];
    const float* bv     = (const float*)d_in[6];
    const float* alphas = (const float*)d_in[7];
    float* out = (float*)d_out;

    const size_t nQ = (size_t)BATCH * HEADS * SEQ * HDIM;
    f16* qf  = (f16*)d_ws;
    f16* kf  = qf + nQ;
    f16* vtf = kf + nQ;
    float* biasTab = (float*)(vtf + nQ);
    f16* Xh = (f16*)(biasTab + 49152);
    f16* Wh = Xh + (size_t)8192 * 768;

    const int prep_threads = NCVT + NBIAS;
    hipLaunchKernelGGL(prep_kernel, dim3((prep_threads + 255) / 256), dim3(256), 0,
                       stream, X, Wq, Wk, Wv, alphas, Xh, Wh, biasTab);
    hipLaunchKernelGGL(qkv_kernel, dim3(1152), dim3(256), 0, stream,
                       Xh, Wh, bq, bk, bv, qf, kf, vtf);
    hipLaunchKernelGGL(attn_kernel, dim3(BATCH * HEADS * 16), dim3(256), 0, stream,
                       qf, kf, vtf, biasTab, out);
}